// Round 3
// baseline (101.943 us; speedup 1.0000x reference)
//
#include <hip/hip_runtime.h>

// Problem constants
constexpr int   kN  = 4096;
constexpr int   kD  = 256;
constexpr float kNU = 3.0f;
constexpr int   kNB = kN / 128;                // 32 block-rows/cols
constexpr int   kNPairs = kNB * (kNB + 1) / 2; // 528 upper-tri block pairs
// Sampled median from diag tile 0, self-pairs excluded
constexpr unsigned kSample0 = 128u * 128u - 128u;        // 16256
constexpr unsigned kTarget0 = (kSample0 - 1u) / 2u + 1u; // lower median rank

using f32x4 = __attribute__((ext_vector_type(4))) float;

// ---------------------------------------------------------------------------
// K1: prep. Blocks 1..1024: fp32->fp8 + norms + coeff (4 rows each).
// Block 0: alpha — self-converts rows 0..127 into swizzled fp8 LDS (bit-
// identical cvt ops), SAME-operand MFMA gram from LDS, histogram median.
// No dependence on other blocks' output => no ordering needed.
// ---------------------------------------------------------------------------
__global__ __launch_bounds__(256) void prep_kernel(
    const float* __restrict__ z, unsigned int* __restrict__ z8,
    float* __restrict__ norms, float* __restrict__ coef,
    float* __restrict__ alpha_p, unsigned int* __restrict__ sync_flags) {
  __shared__ __align__(16) unsigned char tile8[32768];  // [kc][row][swz chunk]
  __shared__ float nT[128];
  int tid = threadIdx.x;
  int w = tid >> 6, lane = tid & 63;

  if (blockIdx.x != 0) {
    if (blockIdx.x == 1 && tid == 0) sync_flags[0] = 0u;  // done counter
    int row = (int)(blockIdx.x - 1) * 4 + w;
    const float4 v = *(const float4*)(z + (size_t)row * kD + lane * 4);
    unsigned p = 0;
    p = __builtin_amdgcn_cvt_pk_fp8_f32(v.x, v.y, p, false);  // bytes 0,1
    p = __builtin_amdgcn_cvt_pk_fp8_f32(v.z, v.w, p, true);   // bytes 2,3
    z8[((size_t)row * kD >> 2) + lane] = p;
    float sq = v.x * v.x + v.y * v.y + v.z * v.z + v.w * v.w;
    for (int off = 32; off > 0; off >>= 1) sq += __shfl_down(sq, off, 64);
    if (lane == 0) {
      norms[row] = sq;
      coef[row] = -(kNU + (float)kD) / (kNU + sq);   // sigma = 1
    }
    return;
  }

  // ---- block 0: alpha ----
  int quad = lane >> 4, l15 = lane & 15;
  int waveM = (w >> 1) * 64, waveN = (w & 1) * 64;

  // Convert rows 0..127 (32 rows per wave) into XOR-swizzled fp8 LDS layout
  // matching gram_tile_fp8's reader: tile8[kc*16384 + r*128 + (c^(r&7))*16 ...]
  for (int i = 0; i < 32; i++) {
    int r = w * 32 + i;
    const float4 v = *(const float4*)(z + (size_t)r * kD + lane * 4);
    unsigned p = 0;
    p = __builtin_amdgcn_cvt_pk_fp8_f32(v.x, v.y, p, false);
    p = __builtin_amdgcn_cvt_pk_fp8_f32(v.z, v.w, p, true);
    int kc = lane >> 5;            // byte col = lane*4; kc = col>>7
    int c  = (lane >> 2) & 7;      // chunk within kc half
    int cp = c ^ (r & 7);
    *(unsigned*)(tile8 + kc * 16384 + r * 128 + cp * 16 + (lane & 3) * 4) = p;
    float sq = v.x * v.x + v.y * v.y + v.z * v.z + v.w * v.w;  // same order
    for (int off = 32; off > 0; off >>= 1) sq += __shfl_down(sq, off, 64);
    if (lane == 0) nT[r] = sq;
  }
  __syncthreads();

  // SAME-operand gram, identical MFMA sequence to previous rounds
  f32x4 acc[4][4] = {};
  for (int kc = 0; kc < 2; kc++) {
    const unsigned char* L = tile8 + kc * 16384;
#pragma unroll
    for (int ks = 0; ks < 4; ks++) {
      int c = ks * 2 + (quad >> 1);
      int intra = (quad & 1) * 8;
      long aL[4], bL[4];
#pragma unroll
      for (int mi = 0; mi < 4; mi++) {
        int row = waveM + mi * 16 + l15;
        int cp = c ^ (row & 7);
        aL[mi] = *(const long*)(L + row * 128 + cp * 16 + intra);
      }
#pragma unroll
      for (int ni = 0; ni < 4; ni++) {
        int row = waveN + ni * 16 + l15;
        int cp = c ^ (row & 7);
        bL[ni] = *(const long*)(L + row * 128 + cp * 16 + intra);
      }
#pragma unroll
      for (int mi = 0; mi < 4; mi++)
#pragma unroll
        for (int ni = 0; ni < 4; ni++)
          acc[mi][ni] = __builtin_amdgcn_mfma_f32_16x16x32_fp8_fp8(
              aL[mi], bL[ni], acc[mi][ni], 0, 0, 0);
    }
  }
  __syncthreads();                         // gram reads done; overlay hist

  unsigned int* hist = (unsigned int*)tile8;   // 16 KB overlay
  for (int i = tid; i < 4096; i += 256) hist[i] = 0;
  __syncthreads();

#pragma unroll
  for (int mi = 0; mi < 4; mi++) {
    int rl0 = waveM + mi * 16 + quad * 4;
#pragma unroll
    for (int r = 0; r < 4; r++) {
      int rl = rl0 + r;
      float ni_ = nT[rl];
#pragma unroll
      for (int nj = 0; nj < 4; nj++) {
        int cl = waveN + nj * 16 + l15;
        if (rl == cl) continue;
        float g = acc[mi][nj][r];
        float dist = fmaxf(ni_ + nT[cl] - 2.0f * g, 0.0f);
        int bin = (int)(dist * 4.0f);
        bin = bin > 4095 ? 4095 : bin;
        atomicAdd(&hist[bin], 1u);
      }
    }
  }
  __syncthreads();

  if (tid < 64) {
    unsigned own = 0;
#pragma unroll
    for (int u = 0; u < 64; u++) own += hist[tid * 64 + u];
    unsigned incl = own;
#pragma unroll
    for (int off = 1; off < 64; off <<= 1) {
      unsigned t = __shfl_up(incl, off, 64);
      if (tid >= off) incl += t;
    }
    unsigned excl = incl - own;
    unsigned long long bal = __ballot(incl >= kTarget0 && excl < kTarget0);
    int chunk = __ffsll((long long)bal) - 1;
    unsigned exclChunk = __shfl(excl, chunk, 64);
    unsigned h = hist[chunk * 64 + tid];
    unsigned fincl = h;
#pragma unroll
    for (int off = 1; off < 64; off <<= 1) {
      unsigned t = __shfl_up(fincl, off, 64);
      if (tid >= off) fincl += t;
    }
    unsigned long long cum = (unsigned long long)exclChunk + (fincl - h);
    if (cum < kTarget0 && cum + h >= kTarget0) {
      int b = chunk * 64 + tid;
      float frac = (float)(kTarget0 - cum) / (float)h;
      float med = ((float)b + frac) * 0.25f;
      alpha_p[0] = 1.0f / (med + 1e-6f);
    }
  }
}

// ---------------------------------------------------------------------------
// fp8 gram tile: 128x128, BK=128 (2 kc iters), global_load_lds staging,
// XOR-swizzled 16B chunks (8 chunks/row), mfma_f32_16x16x32_fp8_fp8.
// ---------------------------------------------------------------------------
__device__ __forceinline__ void gram_tile_fp8(
    const unsigned char* __restrict__ z8, int bRow, int bCol, int tid,
    unsigned char* ldsA, unsigned char* ldsB, f32x4 acc[4][4]) {
  int lane = tid & 63, w = tid >> 6;
  int quad = lane >> 4, l15 = lane & 15;
  int waveM = (w >> 1) * 64, waveN = (w & 1) * 64;

  for (int kc = 0; kc < 2; kc++) {
    if (kc) __syncthreads();
#pragma unroll
    for (int s = 0; s < 4; s++) {
      int slot = (w * 4 + s) * 64 + lane;      // 0..1023, 16 B each
      int row = slot >> 3;                     // 8 chunks per 128-B row
      int cp = slot & 7;
      int c = cp ^ (row & 7);                  // logical chunk stored here
      const unsigned char* gA = z8 + (size_t)(bRow + row) * kD + kc * 128 + c * 16;
      const unsigned char* gB = z8 + (size_t)(bCol + row) * kD + kc * 128 + c * 16;
      __builtin_amdgcn_global_load_lds(
          (const __attribute__((address_space(1))) void*)gA,
          (__attribute__((address_space(3))) void*)(ldsA + (size_t)(w * 4 + s) * 1024),
          16, 0, 0);
      __builtin_amdgcn_global_load_lds(
          (const __attribute__((address_space(1))) void*)gB,
          (__attribute__((address_space(3))) void*)(ldsB + (size_t)(w * 4 + s) * 1024),
          16, 0, 0);
    }
    __syncthreads();
#pragma unroll
    for (int ks = 0; ks < 4; ks++) {           // k = kc*128 + ks*32
      int c = ks * 2 + (quad >> 1);
      int intra = (quad & 1) * 8;
      long aL[4], bL[4];
#pragma unroll
      for (int mi = 0; mi < 4; mi++) {
        int row = waveM + mi * 16 + l15;
        int cp = c ^ (row & 7);
        aL[mi] = *(const long*)(ldsA + row * 128 + cp * 16 + intra);
      }
#pragma unroll
      for (int ni = 0; ni < 4; ni++) {
        int row = waveN + ni * 16 + l15;
        int cp = c ^ (row & 7);
        bL[ni] = *(const long*)(ldsB + row * 128 + cp * 16 + intra);
      }
#pragma unroll
      for (int mi = 0; mi < 4; mi++)
#pragma unroll
        for (int ni = 0; ni < 4; ni++)
          acc[mi][ni] = __builtin_amdgcn_mfma_f32_16x16x32_fp8_fp8(
              aL[mi], bL[ni], acc[mi][ni], 0, 0, 0);
    }
  }
}

__device__ __forceinline__ void tri_decode(int b, int& by, int& bx) {
  int t = b; by = 0;
  while (t >= kNB - by) { t -= kNB - by; by++; }
  bx = by + t;
}

// ---------------------------------------------------------------------------
// K2: main — lean round-0 body (gram + epilogue) + last-block finalize.
// alpha from prep via dispatch boundary (no spins, no acquire in hot path).
// ---------------------------------------------------------------------------
__global__ __launch_bounds__(256, 4) void main_kernel(
    const unsigned char* __restrict__ z8, const float* __restrict__ norms,
    const float* __restrict__ coef, const float* __restrict__ alpha_p,
    unsigned int* __restrict__ sync_flags, double* __restrict__ partials,
    float* __restrict__ out) {
  __shared__ __align__(16) unsigned char smem[32768];
  __shared__ float nR[128], nC[128], cR[128], cC[128];
  __shared__ double dpart[4];
  __shared__ int isLast;
  int tid = threadIdx.x;
  const int bid = blockIdx.x;

  int by, bx; tri_decode(bid, by, bx);
  int bRow = by * 128, bCol = bx * 128;
  if (tid < 128) { nR[tid] = norms[bRow + tid]; cR[tid] = coef[bRow + tid]; }
  else { int u = tid - 128; nC[u] = norms[bCol + u]; cC[u] = coef[bCol + u]; }

  int lane = tid & 63, w = tid >> 6;
  int quad = lane >> 4, l15 = lane & 15;
  int waveM = (w >> 1) * 64, waveN = (w & 1) * 64;

  f32x4 acc[4][4] = {};
  gram_tile_fp8(z8, bRow, bCol, tid, smem, smem + 16384, acc);

  const float alpha = alpha_p[0];
  const bool diag = (by == bx);
  const float wf = diag ? 1.0f : 2.0f;
  float part = 0.0f;
#pragma unroll
  for (int mi = 0; mi < 4; mi++) {
    int rl0 = waveM + mi * 16 + quad * 4;
#pragma unroll
    for (int r = 0; r < 4; r++) {
      int rl = rl0 + r;
      float ni_ = nR[rl];
      float ci  = cR[rl];
#pragma unroll
      for (int nj = 0; nj < 4; nj++) {
        int cl = waveN + nj * 16 + l15;
        float g = acc[mi][nj][r];
        float njv = nC[cl];
        float cj  = cC[cl];
        float dist = fmaxf(ni_ + njv - 2.0f * g, 0.0f);
        float base = fmaf(alpha, dist, 1.0f);
        float rq  = rsqrtf(base);      // K = base^-0.5
        float rq2 = rq * rq;
        float gc  = -alpha * rq * rq2; // grad_coeff
        float ta  = ci * cj * g * rq;
        float tb  = -gc * ci * (ni_ - g);
        float tc  =  gc * cj * (g - njv);
        float lap =  gc * ((float)kD - 3.0f * alpha * dist * rq2);
        float v = ta + tb + tc + lap;
        if (!(diag && rl == cl)) part += wf * v;
      }
    }
  }

  double d = (double)part;
  for (int off = 32; off > 0; off >>= 1) d += __shfl_down(d, off, 64);
  if (lane == 0) dpart[w] = d;
  __syncthreads();

  // ---- Publish partial; last arriving block finalizes (deterministic order)
  if (tid == 0) {
    partials[bid] = dpart[0] + dpart[1] + dpart[2] + dpart[3];
    __threadfence();                             // release partials
    unsigned int old = __hip_atomic_fetch_add(&sync_flags[0], 1u,
                         __ATOMIC_ACQ_REL, __HIP_MEMORY_SCOPE_AGENT);
    isLast = (old == (unsigned)(kNPairs - 1)) ? 1 : 0;
  }
  __syncthreads();

  if (isLast) {
    double s = 0.0;
    for (int i = tid; i < kNPairs; i += 256) s += partials[i];
    for (int off = 32; off > 0; off >>= 1) s += __shfl_down(s, off, 64);
    if (lane == 0) dpart[w] = s;
    __syncthreads();
    if (tid == 0) {
      double tot = dpart[0] + dpart[1] + dpart[2] + dpart[3];
      out[0] = (float)(tot / ((double)kN * (double)(kN - 1)));
    }
  }
}

// ---------------------------------------------------------------------------
extern "C" void kernel_launch(void* const* d_in, const int* in_sizes, int n_in,
                              void* d_out, int out_size, void* d_ws, size_t ws_size,
                              hipStream_t stream) {
  const float* z = (const float*)d_in[0];
  float* out = (float*)d_out;

  char* ws = (char*)d_ws;
  unsigned char* z8 = (unsigned char*)ws;                     // 1 MB fp8
  float* norms = (float*)(ws + (size_t)kN * kD);
  float* coef  = norms + kN;
  float* alpha = coef + kN;
  unsigned int* sync_flags = (unsigned int*)(alpha + 1);      // [0]=done ctr
  double* partials = (double*)(ws + (2 << 20));               // 8-aligned

  prep_kernel<<<kN / 4 + 1, 256, 0, stream>>>(z, (unsigned int*)z8, norms, coef,
                                              alpha, sync_flags);
  main_kernel<<<kNPairs, 256, 0, stream>>>(z8, norms, coef, alpha, sync_flags,
                                           partials, out);
}

// Round 4
// 91.821 us; speedup vs baseline: 1.1102x; 1.1102x over previous
//
#include <hip/hip_runtime.h>

// Problem constants
constexpr int   kN  = 4096;
constexpr int   kD  = 256;
constexpr float kNU = 3.0f;
constexpr int   kNB = kN / 128;                // 32 block-rows/cols
constexpr int   kNPairs = kNB * (kNB + 1) / 2; // 528 upper-tri block pairs
// Sampled median from diag tile 0, self-pairs excluded
constexpr unsigned kSample0 = 128u * 128u - 128u;        // 16256
constexpr unsigned kTarget0 = (kSample0 - 1u) / 2u + 1u; // lower median rank

using f32x4 = __attribute__((ext_vector_type(4))) float;

// ---------------------------------------------------------------------------
// K1: prep. Blocks 1..1024: fp32->fp8 + norms + coeff (4 rows each).
// Block 0: alpha — self-converts rows 0..127 into swizzled fp8 LDS (bit-
// identical cvt ops), SAME-operand MFMA gram from LDS, histogram median.
// No dependence on other blocks' output => no ordering needed.
// NO device-scope fences/atomics anywhere (twice-measured ~20us poison).
// ---------------------------------------------------------------------------
__global__ __launch_bounds__(256) void prep_kernel(
    const float* __restrict__ z, unsigned int* __restrict__ z8,
    float* __restrict__ norms, float* __restrict__ coef,
    float* __restrict__ alpha_p) {
  __shared__ __align__(16) unsigned char tile8[32768];  // [kc][row][swz chunk]
  __shared__ float nT[128];
  int tid = threadIdx.x;
  int w = tid >> 6, lane = tid & 63;

  if (blockIdx.x != 0) {
    int row = (int)(blockIdx.x - 1) * 4 + w;
    const float4 v = *(const float4*)(z + (size_t)row * kD + lane * 4);
    unsigned p = 0;
    p = __builtin_amdgcn_cvt_pk_fp8_f32(v.x, v.y, p, false);  // bytes 0,1
    p = __builtin_amdgcn_cvt_pk_fp8_f32(v.z, v.w, p, true);   // bytes 2,3
    z8[((size_t)row * kD >> 2) + lane] = p;
    float sq = v.x * v.x + v.y * v.y + v.z * v.z + v.w * v.w;
    for (int off = 32; off > 0; off >>= 1) sq += __shfl_down(sq, off, 64);
    if (lane == 0) {
      norms[row] = sq;
      coef[row] = -(kNU + (float)kD) / (kNU + sq);   // sigma = 1
    }
    return;
  }

  // ---- block 0: alpha ----
  int quad = lane >> 4, l15 = lane & 15;
  int waveM = (w >> 1) * 64, waveN = (w & 1) * 64;

  // Convert rows 0..127 (32 rows per wave) into XOR-swizzled fp8 LDS layout
  // matching the gram reader: tile8[kc*16384 + r*128 + (c^(r&7))*16 + ...]
  for (int i = 0; i < 32; i++) {
    int r = w * 32 + i;
    const float4 v = *(const float4*)(z + (size_t)r * kD + lane * 4);
    unsigned p = 0;
    p = __builtin_amdgcn_cvt_pk_fp8_f32(v.x, v.y, p, false);
    p = __builtin_amdgcn_cvt_pk_fp8_f32(v.z, v.w, p, true);
    int kc = lane >> 5;            // byte col = lane*4; kc = col>>7
    int c  = (lane >> 2) & 7;      // chunk within kc half
    int cp = c ^ (r & 7);
    *(unsigned*)(tile8 + kc * 16384 + r * 128 + cp * 16 + (lane & 3) * 4) = p;
    float sq = v.x * v.x + v.y * v.y + v.z * v.z + v.w * v.w;  // same order
    for (int off = 32; off > 0; off >>= 1) sq += __shfl_down(sq, off, 64);
    if (lane == 0) nT[r] = sq;
  }
  __syncthreads();

  // SAME-operand gram, identical MFMA sequence to previous rounds
  f32x4 acc[4][4] = {};
  for (int kc = 0; kc < 2; kc++) {
    const unsigned char* L = tile8 + kc * 16384;
#pragma unroll
    for (int ks = 0; ks < 4; ks++) {
      int c = ks * 2 + (quad >> 1);
      int intra = (quad & 1) * 8;
      long aL[4], bL[4];
#pragma unroll
      for (int mi = 0; mi < 4; mi++) {
        int row = waveM + mi * 16 + l15;
        int cp = c ^ (row & 7);
        aL[mi] = *(const long*)(L + row * 128 + cp * 16 + intra);
      }
#pragma unroll
      for (int ni = 0; ni < 4; ni++) {
        int row = waveN + ni * 16 + l15;
        int cp = c ^ (row & 7);
        bL[ni] = *(const long*)(L + row * 128 + cp * 16 + intra);
      }
#pragma unroll
      for (int mi = 0; mi < 4; mi++)
#pragma unroll
        for (int ni = 0; ni < 4; ni++)
          acc[mi][ni] = __builtin_amdgcn_mfma_f32_16x16x32_fp8_fp8(
              aL[mi], bL[ni], acc[mi][ni], 0, 0, 0);
    }
  }
  __syncthreads();                         // gram reads done; overlay hist

  unsigned int* hist = (unsigned int*)tile8;   // 16 KB overlay
  for (int i = tid; i < 4096; i += 256) hist[i] = 0;
  __syncthreads();

#pragma unroll
  for (int mi = 0; mi < 4; mi++) {
    int rl0 = waveM + mi * 16 + quad * 4;
#pragma unroll
    for (int r = 0; r < 4; r++) {
      int rl = rl0 + r;
      float ni_ = nT[rl];
#pragma unroll
      for (int nj = 0; nj < 4; nj++) {
        int cl = waveN + nj * 16 + l15;
        if (rl == cl) continue;
        float g = acc[mi][nj][r];
        float dist = fmaxf(ni_ + nT[cl] - 2.0f * g, 0.0f);
        int bin = (int)(dist * 4.0f);
        bin = bin > 4095 ? 4095 : bin;
        atomicAdd(&hist[bin], 1u);
      }
    }
  }
  __syncthreads();

  if (tid < 64) {
    unsigned own = 0;
#pragma unroll
    for (int u = 0; u < 64; u++) own += hist[tid * 64 + u];
    unsigned incl = own;
#pragma unroll
    for (int off = 1; off < 64; off <<= 1) {
      unsigned t = __shfl_up(incl, off, 64);
      if (tid >= off) incl += t;
    }
    unsigned excl = incl - own;
    unsigned long long bal = __ballot(incl >= kTarget0 && excl < kTarget0);
    int chunk = __ffsll((long long)bal) - 1;
    unsigned exclChunk = __shfl(excl, chunk, 64);
    unsigned h = hist[chunk * 64 + tid];
    unsigned fincl = h;
#pragma unroll
    for (int off = 1; off < 64; off <<= 1) {
      unsigned t = __shfl_up(fincl, off, 64);
      if (tid >= off) fincl += t;
    }
    unsigned long long cum = (unsigned long long)exclChunk + (fincl - h);
    if (cum < kTarget0 && cum + h >= kTarget0) {
      int b = chunk * 64 + tid;
      float frac = (float)(kTarget0 - cum) / (float)h;
      float med = ((float)b + frac) * 0.25f;
      alpha_p[0] = 1.0f / (med + 1e-6f);
    }
  }
}

// ---------------------------------------------------------------------------
// fp8 gram tile: 128x128, BK=128 (2 kc iters), global_load_lds staging,
// XOR-swizzled 16B chunks (8 chunks/row), mfma_f32_16x16x32_fp8_fp8.
// ---------------------------------------------------------------------------
__device__ __forceinline__ void gram_tile_fp8(
    const unsigned char* __restrict__ z8, int bRow, int bCol, int tid,
    unsigned char* ldsA, unsigned char* ldsB, f32x4 acc[4][4]) {
  int lane = tid & 63, w = tid >> 6;
  int quad = lane >> 4, l15 = lane & 15;
  int waveM = (w >> 1) * 64, waveN = (w & 1) * 64;

  for (int kc = 0; kc < 2; kc++) {
    if (kc) __syncthreads();
#pragma unroll
    for (int s = 0; s < 4; s++) {
      int slot = (w * 4 + s) * 64 + lane;      // 0..1023, 16 B each
      int row = slot >> 3;                     // 8 chunks per 128-B row
      int cp = slot & 7;
      int c = cp ^ (row & 7);                  // logical chunk stored here
      const unsigned char* gA = z8 + (size_t)(bRow + row) * kD + kc * 128 + c * 16;
      const unsigned char* gB = z8 + (size_t)(bCol + row) * kD + kc * 128 + c * 16;
      __builtin_amdgcn_global_load_lds(
          (const __attribute__((address_space(1))) void*)gA,
          (__attribute__((address_space(3))) void*)(ldsA + (size_t)(w * 4 + s) * 1024),
          16, 0, 0);
      __builtin_amdgcn_global_load_lds(
          (const __attribute__((address_space(1))) void*)gB,
          (__attribute__((address_space(3))) void*)(ldsB + (size_t)(w * 4 + s) * 1024),
          16, 0, 0);
    }
    __syncthreads();
#pragma unroll
    for (int ks = 0; ks < 4; ks++) {           // k = kc*128 + ks*32
      int c = ks * 2 + (quad >> 1);
      int intra = (quad & 1) * 8;
      long aL[4], bL[4];
#pragma unroll
      for (int mi = 0; mi < 4; mi++) {
        int row = waveM + mi * 16 + l15;
        int cp = c ^ (row & 7);
        aL[mi] = *(const long*)(ldsA + row * 128 + cp * 16 + intra);
      }
#pragma unroll
      for (int ni = 0; ni < 4; ni++) {
        int row = waveN + ni * 16 + l15;
        int cp = c ^ (row & 7);
        bL[ni] = *(const long*)(ldsB + row * 128 + cp * 16 + intra);
      }
#pragma unroll
      for (int mi = 0; mi < 4; mi++)
#pragma unroll
        for (int ni = 0; ni < 4; ni++)
          acc[mi][ni] = __builtin_amdgcn_mfma_f32_16x16x32_fp8_fp8(
              aL[mi], bL[ni], acc[mi][ni], 0, 0, 0);
    }
  }
}

__device__ __forceinline__ void tri_decode(int b, int& by, int& bx) {
  int t = b; by = 0;
  while (t >= kNB - by) { t -= kNB - by; by++; }
  bx = by + t;
}

// ---------------------------------------------------------------------------
// K2: main — 528 tri blocks: fp8 gram + k_stein loss; plain-store partials.
// No atomics, no fences, no spins; cross-kernel deps via dispatch boundaries.
// ---------------------------------------------------------------------------
__global__ __launch_bounds__(256, 4) void main_kernel(
    const unsigned char* __restrict__ z8, const float* __restrict__ norms,
    const float* __restrict__ coef, const float* __restrict__ alpha_p,
    double* __restrict__ partials) {
  __shared__ __align__(16) unsigned char smem[32768];
  __shared__ float nR[128], nC[128], cR[128], cC[128];
  __shared__ double dpart[4];
  int tid = threadIdx.x;

  int by, bx; tri_decode(blockIdx.x, by, bx);
  int bRow = by * 128, bCol = bx * 128;
  if (tid < 128) { nR[tid] = norms[bRow + tid]; cR[tid] = coef[bRow + tid]; }
  else { int u = tid - 128; nC[u] = norms[bCol + u]; cC[u] = coef[bCol + u]; }

  int lane = tid & 63, w = tid >> 6;
  int quad = lane >> 4, l15 = lane & 15;
  int waveM = (w >> 1) * 64, waveN = (w & 1) * 64;

  f32x4 acc[4][4] = {};
  gram_tile_fp8(z8, bRow, bCol, tid, smem, smem + 16384, acc);

  const float alpha = alpha_p[0];
  const bool diag = (by == bx);
  const float wf = diag ? 1.0f : 2.0f;
  float part = 0.0f;
#pragma unroll
  for (int mi = 0; mi < 4; mi++) {
    int rl0 = waveM + mi * 16 + quad * 4;
#pragma unroll
    for (int r = 0; r < 4; r++) {
      int rl = rl0 + r;
      float ni_ = nR[rl];
      float ci  = cR[rl];
#pragma unroll
      for (int nj = 0; nj < 4; nj++) {
        int cl = waveN + nj * 16 + l15;
        float g = acc[mi][nj][r];
        float njv = nC[cl];
        float cj  = cC[cl];
        float dist = fmaxf(ni_ + njv - 2.0f * g, 0.0f);
        float base = fmaf(alpha, dist, 1.0f);
        float rq  = rsqrtf(base);      // K = base^-0.5
        float rq2 = rq * rq;
        float gc  = -alpha * rq * rq2; // grad_coeff
        float ta  = ci * cj * g * rq;
        float tb  = -gc * ci * (ni_ - g);
        float tc  =  gc * cj * (g - njv);
        float lap =  gc * ((float)kD - 3.0f * alpha * dist * rq2);
        float v = ta + tb + tc + lap;
        if (!(diag && rl == cl)) part += wf * v;
      }
    }
  }

  double d = (double)part;
  for (int off = 32; off > 0; off >>= 1) d += __shfl_down(d, off, 64);
  if (lane == 0) dpart[w] = d;
  __syncthreads();
  if (tid == 0) partials[blockIdx.x] = dpart[0] + dpart[1] + dpart[2] + dpart[3];
}

// ---------------------------------------------------------------------------
// K3: finalize — one block sums 528 partials (deterministic order)
// ---------------------------------------------------------------------------
__global__ __launch_bounds__(256) void finalize_kernel(
    const double* __restrict__ partials, float* __restrict__ out) {
  __shared__ double dpart[4];
  int tid = threadIdx.x;
  int lane = tid & 63, w = tid >> 6;
  double s = 0.0;
  for (int i = tid; i < kNPairs; i += 256) s += partials[i];
  for (int off = 32; off > 0; off >>= 1) s += __shfl_down(s, off, 64);
  if (lane == 0) dpart[w] = s;
  __syncthreads();
  if (tid == 0) {
    double tot = dpart[0] + dpart[1] + dpart[2] + dpart[3];
    out[0] = (float)(tot / ((double)kN * (double)(kN - 1)));
  }
}

// ---------------------------------------------------------------------------
extern "C" void kernel_launch(void* const* d_in, const int* in_sizes, int n_in,
                              void* d_out, int out_size, void* d_ws, size_t ws_size,
                              hipStream_t stream) {
  const float* z = (const float*)d_in[0];
  float* out = (float*)d_out;

  char* ws = (char*)d_ws;
  unsigned char* z8 = (unsigned char*)ws;                     // 1 MB fp8
  float* norms = (float*)(ws + (size_t)kN * kD);
  float* coef  = norms + kN;
  float* alpha = coef + kN;
  double* partials = (double*)(ws + (2 << 20));               // 8-aligned

  prep_kernel<<<kN / 4 + 1, 256, 0, stream>>>(z, (unsigned int*)z8, norms, coef,
                                              alpha);
  main_kernel<<<kNPairs, 256, 0, stream>>>(z8, norms, coef, alpha, partials);
  finalize_kernel<<<1, 256, 0, stream>>>(partials, out);
}

// Round 5
// 84.879 us; speedup vs baseline: 1.2010x; 1.0818x over previous
//
#include <hip/hip_runtime.h>

// Problem constants
constexpr int   kN  = 4096;
constexpr int   kD  = 256;
constexpr float kNU = 3.0f;
constexpr int   kNB = kN / 128;                // 32 block-rows/cols
constexpr int   kNPairs = kNB * (kNB + 1) / 2; // 528 upper-tri block pairs
// Sampled median from diag tile 0, self-pairs excluded
constexpr unsigned kSample0 = 128u * 128u - 128u;        // 16256
constexpr unsigned kTarget0 = (kSample0 - 1u) / 2u + 1u; // lower median rank

using f32x4 = __attribute__((ext_vector_type(4))) float;

// ---------------------------------------------------------------------------
// K1: per-row norms + coeff + fp32 -> fp8(e4m3) conversion. (R0-proven)
// ---------------------------------------------------------------------------
__global__ __launch_bounds__(256) void prep_kernel(
    const float* __restrict__ z, unsigned int* __restrict__ z8,
    float* __restrict__ norms, float* __restrict__ coef) {
  int tid = threadIdx.x;
  int w = tid >> 6, lane = tid & 63;
  int row = blockIdx.x * 4 + w;
  const float4 v = *(const float4*)(z + (size_t)row * kD + lane * 4);

  unsigned p = 0;
  p = __builtin_amdgcn_cvt_pk_fp8_f32(v.x, v.y, p, false);  // bytes 0,1
  p = __builtin_amdgcn_cvt_pk_fp8_f32(v.z, v.w, p, true);   // bytes 2,3
  z8[((size_t)row * kD >> 2) + lane] = p;

  float sq = v.x * v.x + v.y * v.y + v.z * v.z + v.w * v.w;
  for (int off = 32; off > 0; off >>= 1) sq += __shfl_down(sq, off, 64);
  if (lane == 0) {
    norms[row] = sq;
    coef[row] = -(kNU + (float)kD) / (kNU + sq);   // sigma = 1
  }
}

// ---------------------------------------------------------------------------
// Staging: one 128-row x 128-B (half-K) panel into a private LDS buffer via
// global_load_lds, XOR-swizzled 16B chunks. 4 instrs/thread, no waits here.
// ---------------------------------------------------------------------------
__device__ __forceinline__ void stage_panel(
    const unsigned char* __restrict__ z8, int bRow, int kc, int tid,
    unsigned char* dst) {
  int lane = tid & 63, w = tid >> 6;
#pragma unroll
  for (int s = 0; s < 4; s++) {
    int slot = (w * 4 + s) * 64 + lane;      // 0..1023, 16 B each
    int row = slot >> 3;                     // 8 chunks per 128-B row
    int cp = slot & 7;
    int c = cp ^ (row & 7);                  // logical chunk stored here
    const unsigned char* g = z8 + (size_t)(bRow + row) * kD + kc * 128 + c * 16;
    __builtin_amdgcn_global_load_lds(
        (const __attribute__((address_space(1))) void*)g,
        (__attribute__((address_space(3))) void*)(dst + (size_t)(w * 4 + s) * 1024),
        16, 0, 0);
  }
}

// ---------------------------------------------------------------------------
// Compute: one half-K (128) gram contribution from staged LDS panels.
// MFMA order identical to all previous rounds (ks 0..3, mi x ni inner).
// ---------------------------------------------------------------------------
__device__ __forceinline__ void gram_kc(
    const unsigned char* LA, const unsigned char* LB, int tid,
    f32x4 acc[4][4]) {
  int lane = tid & 63, w = tid >> 6;
  int quad = lane >> 4, l15 = lane & 15;
  int waveM = (w >> 1) * 64, waveN = (w & 1) * 64;
#pragma unroll
  for (int ks = 0; ks < 4; ks++) {
    int c = ks * 2 + (quad >> 1);
    int intra = (quad & 1) * 8;
    long aL[4], bL[4];
#pragma unroll
    for (int mi = 0; mi < 4; mi++) {
      int row = waveM + mi * 16 + l15;
      int cp = c ^ (row & 7);
      aL[mi] = *(const long*)(LA + row * 128 + cp * 16 + intra);
    }
#pragma unroll
    for (int ni = 0; ni < 4; ni++) {
      int row = waveN + ni * 16 + l15;
      int cp = c ^ (row & 7);
      bL[ni] = *(const long*)(LB + row * 128 + cp * 16 + intra);
    }
#pragma unroll
    for (int mi = 0; mi < 4; mi++)
#pragma unroll
      for (int ni = 0; ni < 4; ni++)
        acc[mi][ni] = __builtin_amdgcn_mfma_f32_16x16x32_fp8_fp8(
            aL[mi], bL[ni], acc[mi][ni], 0, 0, 0);
  }
}

__device__ __forceinline__ void tri_decode(int b, int& by, int& bx) {
  int t = b; by = 0;
  while (t >= kNB - by) { t -= kNB - by; by++; }
  bx = by + t;
}

// ---------------------------------------------------------------------------
// K2: main — per block: redundant alpha (tile-0 SAME-gram + LDS histogram,
// bit-identical across blocks) then own-tile gram + k_stein epilogue.
// Double-buffered LDS: each K-half has a private buffer, so each gram needs
// ONE barrier / ONE vmcnt drain (vs 3 barriers before). No fences/atomics
// to global anywhere (twice-measured ~20us poison).
// ---------------------------------------------------------------------------
__global__ __launch_bounds__(256, 2) void main_kernel(
    const unsigned char* __restrict__ z8, const float* __restrict__ norms,
    const float* __restrict__ coef, double* __restrict__ partials) {
  __shared__ __align__(16) unsigned char smem[65536];  // A0 A1 B0 B1
  __shared__ float nR[128], nC[128], cR[128], cC[128], nT[128];
  __shared__ double dpart[4];
  __shared__ float alpha_sh;
  int tid = threadIdx.x;

  unsigned char* A0 = smem;
  unsigned char* A1 = smem + 16384;
  unsigned char* B0 = smem + 32768;
  unsigned char* B1 = smem + 49152;
  unsigned int* hist = (unsigned int*)B0;   // 16 KB overlay, dead during alpha

  int by, bx; tri_decode(blockIdx.x, by, bx);
  int bRow = by * 128, bCol = bx * 128;
  if (tid < 128) {
    nR[tid] = norms[bRow + tid]; cR[tid] = coef[bRow + tid];
    nT[tid] = norms[tid];
  } else {
    int u = tid - 128; nC[u] = norms[bCol + u]; cC[u] = coef[bCol + u];
  }

  int lane = tid & 63, w = tid >> 6;
  int quad = lane >> 4, l15 = lane & 15;
  int waveM = (w >> 1) * 64, waveN = (w & 1) * 64;

  // ---- Phase A: alpha from tile (0,0) --------------------------------------
  for (int i = tid; i < 4096; i += 256) hist[i] = 0;
  stage_panel(z8, 0, 0, tid, A0);          // tile0 K-half 0
  stage_panel(z8, 0, 1, tid, A1);          // tile0 K-half 1
  __syncthreads();                          // drains vmcnt; hist zeroed; nT set

  f32x4 acc[4][4] = {};
  gram_kc(A0, A0, tid, acc);               // SAME-operand gram, kc order as R2
  gram_kc(A1, A1, tid, acc);

#pragma unroll
  for (int mi = 0; mi < 4; mi++) {
    int rl0 = waveM + mi * 16 + quad * 4;
#pragma unroll
    for (int r = 0; r < 4; r++) {
      int rl = rl0 + r;
      float ni_ = nT[rl];
#pragma unroll
      for (int nj = 0; nj < 4; nj++) {
        int cl = waveN + nj * 16 + l15;
        if (rl == cl) continue;
        float g = acc[mi][nj][r];
        float dist = fmaxf(ni_ + nT[cl] - 2.0f * g, 0.0f);
        int bin = (int)(dist * 4.0f);
        bin = bin > 4095 ? 4095 : bin;
        atomicAdd(&hist[bin], 1u);
      }
    }
  }
  __syncthreads();

  if (tid < 64) {
    unsigned own = 0;
#pragma unroll
    for (int u = 0; u < 64; u++) own += hist[tid * 64 + u];
    unsigned incl = own;
#pragma unroll
    for (int off = 1; off < 64; off <<= 1) {
      unsigned t = __shfl_up(incl, off, 64);
      if (tid >= off) incl += t;
    }
    unsigned excl = incl - own;
    unsigned long long bal = __ballot(incl >= kTarget0 && excl < kTarget0);
    int chunk = __ffsll((long long)bal) - 1;
    unsigned exclChunk = __shfl(excl, chunk, 64);
    unsigned h = hist[chunk * 64 + tid];
    unsigned fincl = h;
#pragma unroll
    for (int off = 1; off < 64; off <<= 1) {
      unsigned t = __shfl_up(fincl, off, 64);
      if (tid >= off) fincl += t;
    }
    unsigned long long cum = (unsigned long long)exclChunk + (fincl - h);
    if (cum < kTarget0 && cum + h >= kTarget0) {
      int b = chunk * 64 + tid;
      float frac = (float)(kTarget0 - cum) / (float)h;
      float med = ((float)b + frac) * 0.25f;
      alpha_sh = 1.0f / (med + 1e-6f);
    }
  }
  __syncthreads();                          // alpha_sh visible; hist dead
  const float alpha = alpha_sh;

  // ---- Phase B: own-tile gram ---------------------------------------------
  stage_panel(z8, bRow, 0, tid, A0);        // 16 instrs, all in flight at once
  stage_panel(z8, bRow, 1, tid, A1);
  stage_panel(z8, bCol, 0, tid, B0);
  stage_panel(z8, bCol, 1, tid, B1);
#pragma unroll
  for (int mi = 0; mi < 4; mi++)
#pragma unroll
    for (int nj = 0; nj < 4; nj++)
#pragma unroll
      for (int k = 0; k < 4; k++) acc[mi][nj][k] = 0.0f;
  __syncthreads();                          // single drain for both K-halves

  gram_kc(A0, B0, tid, acc);
  gram_kc(A1, B1, tid, acc);

  // ---- Epilogue: k_stein partial (identical math to all rounds) -----------
  const bool diag = (by == bx);
  const float wf = diag ? 1.0f : 2.0f;
  float part = 0.0f;
#pragma unroll
  for (int mi = 0; mi < 4; mi++) {
    int rl0 = waveM + mi * 16 + quad * 4;
#pragma unroll
    for (int r = 0; r < 4; r++) {
      int rl = rl0 + r;
      float ni_ = nR[rl];
      float ci  = cR[rl];
#pragma unroll
      for (int nj = 0; nj < 4; nj++) {
        int cl = waveN + nj * 16 + l15;
        float g = acc[mi][nj][r];
        float njv = nC[cl];
        float cj  = cC[cl];
        float dist = fmaxf(ni_ + njv - 2.0f * g, 0.0f);
        float base = fmaf(alpha, dist, 1.0f);
        float rq  = rsqrtf(base);      // K = base^-0.5
        float rq2 = rq * rq;
        float gc  = -alpha * rq * rq2; // grad_coeff
        float ta  = ci * cj * g * rq;
        float tb  = -gc * ci * (ni_ - g);
        float tc  =  gc * cj * (g - njv);
        float lap =  gc * ((float)kD - 3.0f * alpha * dist * rq2);
        float v = ta + tb + tc + lap;
        if (!(diag && rl == cl)) part += wf * v;
      }
    }
  }

  double d = (double)part;
  for (int off = 32; off > 0; off >>= 1) d += __shfl_down(d, off, 64);
  if (lane == 0) dpart[w] = d;
  __syncthreads();
  if (tid == 0) partials[blockIdx.x] = dpart[0] + dpart[1] + dpart[2] + dpart[3];
}

// ---------------------------------------------------------------------------
// K3: finalize — one block sums 528 partials (deterministic order)
// ---------------------------------------------------------------------------
__global__ __launch_bounds__(256) void finalize_kernel(
    const double* __restrict__ partials, float* __restrict__ out) {
  __shared__ double dpart[4];
  int tid = threadIdx.x;
  int lane = tid & 63, w = tid >> 6;
  double s = 0.0;
  for (int i = tid; i < kNPairs; i += 256) s += partials[i];
  for (int off = 32; off > 0; off >>= 1) s += __shfl_down(s, off, 64);
  if (lane == 0) dpart[w] = s;
  __syncthreads();
  if (tid == 0) {
    double tot = dpart[0] + dpart[1] + dpart[2] + dpart[3];
    out[0] = (float)(tot / ((double)kN * (double)(kN - 1)));
  }
}

// ---------------------------------------------------------------------------
extern "C" void kernel_launch(void* const* d_in, const int* in_sizes, int n_in,
                              void* d_out, int out_size, void* d_ws, size_t ws_size,
                              hipStream_t stream) {
  const float* z = (const float*)d_in[0];
  float* out = (float*)d_out;

  char* ws = (char*)d_ws;
  unsigned char* z8 = (unsigned char*)ws;                     // 1 MB fp8
  float* norms = (float*)(ws + (size_t)kN * kD);
  float* coef  = norms + kN;
  double* partials = (double*)(ws + (2 << 20));               // 8-aligned

  prep_kernel<<<kN / 4, 256, 0, stream>>>(z, (unsigned int*)z8, norms, coef);
  main_kernel<<<kNPairs, 256, 0, stream>>>(z8, norms, coef, partials);
  finalize_kernel<<<1, 256, 0, stream>>>(partials, out);
}

// Round 7
// 79.425 us; speedup vs baseline: 1.2835x; 1.0687x over previous
//
#include <hip/hip_runtime.h>

// Problem constants
constexpr int   kN  = 4096;
constexpr int   kD  = 256;
constexpr float kNU = 3.0f;
constexpr int   kNB = kN / 128;                // 32 block-rows/cols
constexpr int   kNPairs = kNB * (kNB + 1) / 2; // 528 upper-tri block pairs
// Sampled median from diag tile 0, self-pairs excluded
constexpr unsigned kSample0 = 128u * 128u - 128u;        // 16256
constexpr unsigned kTarget0 = (kSample0 - 1u) / 2u + 1u; // lower median rank

using f32x4 = __attribute__((ext_vector_type(4))) float;

// ---------------------------------------------------------------------------
// K1: per-row norms + coeff + fp32 -> fp8(e4m3) conversion. (R0-proven)
// ---------------------------------------------------------------------------
__global__ __launch_bounds__(256) void prep_kernel(
    const float* __restrict__ z, unsigned int* __restrict__ z8,
    float* __restrict__ norms, float* __restrict__ coef) {
  int tid = threadIdx.x;
  int w = tid >> 6, lane = tid & 63;
  int row = blockIdx.x * 4 + w;
  const float4 v = *(const float4*)(z + (size_t)row * kD + lane * 4);

  unsigned p = 0;
  p = __builtin_amdgcn_cvt_pk_fp8_f32(v.x, v.y, p, false);  // bytes 0,1
  p = __builtin_amdgcn_cvt_pk_fp8_f32(v.z, v.w, p, true);   // bytes 2,3
  z8[((size_t)row * kD >> 2) + lane] = p;

  float sq = v.x * v.x + v.y * v.y + v.z * v.z + v.w * v.w;
  for (int off = 32; off > 0; off >>= 1) sq += __shfl_down(sq, off, 64);
  if (lane == 0) {
    norms[row] = sq;
    coef[row] = -(kNU + (float)kD) / (kNU + sq);   // sigma = 1
  }
}

// ---------------------------------------------------------------------------
// Staging: one 128-row x 128-B (half-K) panel into a private LDS buffer via
// global_load_lds, XOR-swizzled 16B chunks. 4 instrs/thread, no waits here.
// ---------------------------------------------------------------------------
__device__ __forceinline__ void stage_panel(
    const unsigned char* __restrict__ z8, int bRow, int kc, int tid,
    unsigned char* dst) {
  int lane = tid & 63, w = tid >> 6;
#pragma unroll
  for (int s = 0; s < 4; s++) {
    int slot = (w * 4 + s) * 64 + lane;      // 0..1023, 16 B each
    int row = slot >> 3;                     // 8 chunks per 128-B row
    int cp = slot & 7;
    int c = cp ^ (row & 7);                  // logical chunk stored here
    const unsigned char* g = z8 + (size_t)(bRow + row) * kD + kc * 128 + c * 16;
    __builtin_amdgcn_global_load_lds(
        (const __attribute__((address_space(1))) void*)g,
        (__attribute__((address_space(3))) void*)(dst + (size_t)(w * 4 + s) * 1024),
        16, 0, 0);
  }
}

// ---------------------------------------------------------------------------
// Compute: one half-K (128) gram contribution from staged LDS panels.
// MFMA order identical to all previous rounds (ks 0..3, mi x ni inner).
// ---------------------------------------------------------------------------
__device__ __forceinline__ void gram_kc(
    const unsigned char* LA, const unsigned char* LB, int tid,
    f32x4 acc[4][4]) {
  int lane = tid & 63, w = tid >> 6;
  int quad = lane >> 4, l15 = lane & 15;
  int waveM = (w >> 1) * 64, waveN = (w & 1) * 64;
#pragma unroll
  for (int ks = 0; ks < 4; ks++) {
    int c = ks * 2 + (quad >> 1);
    int intra = (quad & 1) * 8;
    long aL[4], bL[4];
#pragma unroll
    for (int mi = 0; mi < 4; mi++) {
      int row = waveM + mi * 16 + l15;
      int cp = c ^ (row & 7);
      aL[mi] = *(const long*)(LA + row * 128 + cp * 16 + intra);
    }
#pragma unroll
    for (int ni = 0; ni < 4; ni++) {
      int row = waveN + ni * 16 + l15;
      int cp = c ^ (row & 7);
      bL[ni] = *(const long*)(LB + row * 128 + cp * 16 + intra);
    }
#pragma unroll
    for (int mi = 0; mi < 4; mi++)
#pragma unroll
      for (int ni = 0; ni < 4; ni++)
        acc[mi][ni] = __builtin_amdgcn_mfma_f32_16x16x32_fp8_fp8(
            aL[mi], bL[ni], acc[mi][ni], 0, 0, 0);
  }
}

__device__ __forceinline__ void tri_decode(int b, int& by, int& bx) {
  int t = b; by = 0;
  while (t >= kNB - by) { t -= kNB - by; by++; }
  bx = by + t;
}

// ---------------------------------------------------------------------------
// K2: main — per block: redundant alpha (tile-0 gram + LDS histogram, bit-
// identical across blocks; hist/scan source verbatim from R2/R5) then own-
// tile gram + trimmed k_stein epilogue. Hist lives in its own 16KB so the
// phase-B kc0 panels prefetch during hist/scan; A-kc1 prefetches into the
// dead hist space during the kc0 gram. No global fences/atomics (poison).
// ---------------------------------------------------------------------------
__global__ __launch_bounds__(256, 3) void main_kernel(
    const unsigned char* __restrict__ z8, const float* __restrict__ norms,
    const float* __restrict__ coef, double* __restrict__ partials) {
  __shared__ __align__(16) unsigned char smem[49152];  // S0 | S1 | H
  __shared__ float nR[128], nC[128], cR[128], cC[128], nT[128];
  __shared__ double dpart[4];
  __shared__ float alpha_sh;
  int tid = threadIdx.x;

  unsigned char* S0 = smem;
  unsigned char* S1 = smem + 16384;
  unsigned char* H  = smem + 32768;
  unsigned int* hist = (unsigned int*)H;

  int by, bx; tri_decode(blockIdx.x, by, bx);
  int bRow = by * 128, bCol = bx * 128;
  if (tid < 128) {
    nR[tid] = norms[bRow + tid]; cR[tid] = coef[bRow + tid];
    nT[tid] = norms[tid];
  } else {
    int u = tid - 128; nC[u] = norms[bCol + u]; cC[u] = coef[bCol + u];
  }

  int lane = tid & 63, w = tid >> 6;
  int quad = lane >> 4, l15 = lane & 15;
  int waveM = (w >> 1) * 64, waveN = (w & 1) * 64;

  // ---- Phase A: alpha from tile (0,0) -------------------------------------
  for (int i = tid; i < 4096; i += 256) hist[i] = 0;
  stage_panel(z8, 0, 0, tid, S0);
  stage_panel(z8, 0, 1, tid, S1);
  __syncthreads();                          // (1) drains; aux/hist-zero done

  f32x4 acc[4][4] = {};
  gram_kc(S0, S0, tid, acc);               // SAME-operand gram (R5-proven)
  gram_kc(S1, S1, tid, acc);
  __syncthreads();                          // (2) S0/S1 readers done

  // Prefetch phase-B kc0 panels; latency hides under hist + scan.
  stage_panel(z8, bRow, 0, tid, S0);
  stage_panel(z8, bCol, 0, tid, S1);

  {
    float nT4[4];
#pragma unroll
    for (int nj = 0; nj < 4; nj++) nT4[nj] = nT[waveN + nj * 16 + l15];
#pragma unroll
    for (int mi = 0; mi < 4; mi++) {
      int rl0 = waveM + mi * 16 + quad * 4;
#pragma unroll
      for (int r = 0; r < 4; r++) {
        int rl = rl0 + r;
        float ni_ = nT[rl];
#pragma unroll
        for (int nj = 0; nj < 4; nj++) {
          int cl = waveN + nj * 16 + l15;
          if (rl == cl) continue;
          float g = acc[mi][nj][r];
          float dist = fmaxf(ni_ + nT4[nj] - 2.0f * g, 0.0f);
          int bin = (int)(dist * 4.0f);
          bin = bin > 4095 ? 4095 : bin;
          atomicAdd(&hist[bin], 1u);
        }
      }
    }
  }
  __syncthreads();                          // (3) hist done; kc0 drained

  if (tid < 64) {
    unsigned own = 0;
#pragma unroll
    for (int u = 0; u < 64; u++) own += hist[tid * 64 + u];
    unsigned incl = own;
#pragma unroll
    for (int off = 1; off < 64; off <<= 1) {
      unsigned t = __shfl_up(incl, off, 64);
      if (tid >= off) incl += t;
    }
    unsigned excl = incl - own;
    unsigned long long bal = __ballot(incl >= kTarget0 && excl < kTarget0);
    int chunk = __ffsll((long long)bal) - 1;
    unsigned exclChunk = __shfl(excl, chunk, 64);
    unsigned h = hist[chunk * 64 + tid];
    unsigned fincl = h;
#pragma unroll
    for (int off = 1; off < 64; off <<= 1) {
      unsigned t = __shfl_up(fincl, off, 64);
      if (tid >= off) fincl += t;
    }
    unsigned long long cum = (unsigned long long)exclChunk + (fincl - h);
    if (cum < kTarget0 && cum + h >= kTarget0) {
      int b = chunk * 64 + tid;
      float frac = (float)(kTarget0 - cum) / (float)h;
      float med = ((float)b + frac) * 0.25f;
      alpha_sh = 1.0f / (med + 1e-6f);
    }
  }
  __syncthreads();                          // (4) alpha_sh visible; H dead
  const float alpha = alpha_sh;

  // ---- Phase B: own-tile gram ---------------------------------------------
  stage_panel(z8, bRow, 1, tid, H);         // A-kc1 into dead hist space
#pragma unroll
  for (int mi = 0; mi < 4; mi++)
#pragma unroll
    for (int nj = 0; nj < 4; nj++)
#pragma unroll
      for (int k = 0; k < 4; k++) acc[mi][nj][k] = 0.0f;

  gram_kc(S0, S1, tid, acc);                // kc0 (A in S0, B in S1)
  __syncthreads();                          // (5) S0 free; A-kc1 drained
  stage_panel(z8, bCol, 1, tid, S0);        // B-kc1 into dead S0
  __syncthreads();                          // (6) drain B-kc1
  gram_kc(H, S0, tid, acc);                 // kc1 (A in H, B in S0)

  // ---- Epilogue: trimmed k_stein partial ----------------------------------
  // v = ci*cj*g*rq + am*( ci*(ni-g) + cj*(njv-g) - (D-3+3*rq2) )
  // using alpha*dist*rq2 == 1 - rq2 (base = 1+alpha*dist, rq2 = 1/base).
  // wf hoisted out of the sum: x2 is exact scaling => partial bit-identical.
  const bool diag = (by == bx);
  const float wf = diag ? 1.0f : 2.0f;
  const float Dm3 = (float)kD - 3.0f;
  float njv4[4], cj4[4];
#pragma unroll
  for (int nj = 0; nj < 4; nj++) {
    int cl = waveN + nj * 16 + l15;
    njv4[nj] = nC[cl]; cj4[nj] = cC[cl];
  }
  float part = 0.0f;
#pragma unroll
  for (int mi = 0; mi < 4; mi++) {
    int rl0 = waveM + mi * 16 + quad * 4;
#pragma unroll
    for (int r = 0; r < 4; r++) {
      int rl = rl0 + r;
      float ni_ = nR[rl];
      float ci  = cR[rl];
#pragma unroll
      for (int nj = 0; nj < 4; nj++) {
        int cl = waveN + nj * 16 + l15;
        float g   = acc[mi][nj][r];
        float njv = njv4[nj];
        float cj  = cj4[nj];
        float s    = ni_ + njv;
        float dist = fmaxf(fmaf(-2.0f, g, s), 0.0f);
        float base = fmaf(alpha, dist, 1.0f);
        float rq   = rsqrtf(base);          // K = base^-0.5
        float rq2  = rq * rq;
        float am   = alpha * (rq * rq2);    // = -grad_coeff
        float W    = fmaf(3.0f, rq2, Dm3);  // (D-3) + 3*rq2
        float inner = fmaf(ci, ni_ - g, fmaf(cj, njv - g, -W));
        float v    = fmaf(ci * cj * g, rq, am * inner);
        if (!(diag && rl == cl)) part += v;
      }
    }
  }
  part *= wf;

  double d = (double)part;
  for (int off = 32; off > 0; off >>= 1) d += __shfl_down(d, off, 64);
  if (lane == 0) dpart[w] = d;
  __syncthreads();                          // (7)
  if (tid == 0) partials[blockIdx.x] = dpart[0] + dpart[1] + dpart[2] + dpart[3];
}

// ---------------------------------------------------------------------------
// K3: finalize — one block sums 528 partials (deterministic order)
// ---------------------------------------------------------------------------
__global__ __launch_bounds__(256) void finalize_kernel(
    const double* __restrict__ partials, float* __restrict__ out) {
  __shared__ double dpart[4];
  int tid = threadIdx.x;
  int lane = tid & 63, w = tid >> 6;
  double s = 0.0;
  for (int i = tid; i < kNPairs; i += 256) s += partials[i];
  for (int off = 32; off > 0; off >>= 1) s += __shfl_down(s, off, 64);
  if (lane == 0) dpart[w] = s;
  __syncthreads();
  if (tid == 0) {
    double tot = dpart[0] + dpart[1] + dpart[2] + dpart[3];
    out[0] = (float)(tot / ((double)kN * (double)(kN - 1)));
  }
}

// ---------------------------------------------------------------------------
extern "C" void kernel_launch(void* const* d_in, const int* in_sizes, int n_in,
                              void* d_out, int out_size, void* d_ws, size_t ws_size,
                              hipStream_t stream) {
  const float* z = (const float*)d_in[0];
  float* out = (float*)d_out;

  char* ws = (char*)d_ws;
  unsigned char* z8 = (unsigned char*)ws;                     // 1 MB fp8
  float* norms = (float*)(ws + (size_t)kN * kD);
  float* coef  = norms + kN;
  double* partials = (double*)(ws + (2 << 20));               // 8-aligned

  prep_kernel<<<kN / 4, 256, 0, stream>>>(z, (unsigned int*)z8, norms, coef);
  main_kernel<<<kNPairs, 256, 0, stream>>>(z8, norms, coef, partials);
  finalize_kernel<<<1, 256, 0, stream>>>(partials, out);
}